// Round 1
// baseline (1733.276 us; speedup 1.0000x reference)
//
#include <hip/hip_runtime.h>

#define NN 8192
#define HH 64
constexpr float LALPHA = 0.2f;

// ---------------------------------------------------------------- diag extract
__global__ __launch_bounds__(256) void k_diag(const float* __restrict__ na,
                                              const float* __restrict__ ea,
                                              float* __restrict__ dn,
                                              float* __restrict__ de) {
  int i = blockIdx.x * 256 + threadIdx.x;
  if (i < NN) {
    dn[i] = na[(size_t)i * NN + i];
    de[i] = ea[(size_t)i * NN + i];
  }
}

// ---------------------------------------------------------------- column sums of h
__global__ __launch_bounds__(256) void k_hbarP(const float* __restrict__ h,
                                               float* __restrict__ HbP) {
  int c = threadIdx.x & 63, rs = threadIdx.x >> 6;
  int r0 = blockIdx.x * 128;
  float s = 0.f;
  for (int r = rs; r < 128; r += 4) s += h[(size_t)(r0 + r) * HH + c];
  __shared__ float red[4][64];
  red[rs][c] = s;
  __syncthreads();
  if (rs == 0) HbP[blockIdx.x * 64 + c] = red[0][c] + red[1][c] + red[2][c] + red[3][c];
}

__global__ __launch_bounds__(64) void k_hbarF(const float* __restrict__ HbP,
                                              float* __restrict__ Hb) {
  int c = threadIdx.x;
  float s = 0.f;
  for (int b = 0; b < 64; ++b) s += HbP[b * 64 + c];
  Hb[c] = s;
}

// ---------------------------------------------------------------- heavy masked matmuls
// Sp_raw = (node_adj>0)@h   (diag corrected later)
// Tf_raw = edge_adj@h, Tp_raw = relu(edge_adj)@h, cp_raw = #(edge_adj>0)
// Each wave owns 4 rows; lanes = h-columns; adjacency loads are wave-uniform
// float4 (single 16B request), h loads are 256B coalesced (L2-resident).
__global__ __launch_bounds__(256) void k_stageA(
    const float* __restrict__ na, const float* __restrict__ ea,
    const float* __restrict__ h,
    float* __restrict__ SpP, float* __restrict__ TfP,
    float* __restrict__ TpP, float* __restrict__ cpP) {
  const int lane = threadIdx.x & 63;
  const int wid  = threadIdx.x >> 6;
  const int i0   = blockIdx.x * 16 + wid * 4;
  const int js   = blockIdx.y;
  const int jb   = js * (NN / 2);

  float sp[4] = {0.f, 0.f, 0.f, 0.f};
  float tf[4] = {0.f, 0.f, 0.f, 0.f};
  float tp[4] = {0.f, 0.f, 0.f, 0.f};
  float cp[4] = {0.f, 0.f, 0.f, 0.f};

  for (int j = jb; j < jb + NN / 2; j += 4) {
    float hv[4];
#pragma unroll
    for (int q = 0; q < 4; ++q) hv[q] = h[(size_t)(j + q) * HH + lane];
#pragma unroll
    for (int r = 0; r < 4; ++r) {
      const int row = i0 + r;
      const float4 a4 = *reinterpret_cast<const float4*>(&na[(size_t)row * NN + j]);
      const float4 e4 = *reinterpret_cast<const float4*>(&ea[(size_t)row * NN + j]);
      const float av[4] = {a4.x, a4.y, a4.z, a4.w};
      const float ev[4] = {e4.x, e4.y, e4.z, e4.w};
#pragma unroll
      for (int q = 0; q < 4; ++q) {
        sp[r] += (av[q] > 0.f) ? hv[q] : 0.f;
        tf[r] += ev[q] * hv[q];
        tp[r] += fmaxf(ev[q], 0.f) * hv[q];
        cp[r] += (ev[q] > 0.f) ? 1.f : 0.f;
      }
    }
  }
  const size_t o = (size_t)js * ((size_t)NN * HH);
#pragma unroll
  for (int r = 0; r < 4; ++r) {
    size_t idx = (size_t)(i0 + r) * HH + lane;
    SpP[o + idx] = sp[r];
    TfP[o + idx] = tf[r];
    TpP[o + idx] = tp[r];
    if (lane == 0) cpP[js * NN + i0 + r] = cp[r];
  }
}

// ---------------------------------------------------------------- combine partials
__global__ __launch_bounds__(256) void k_combine(
    const float* __restrict__ h, const float* __restrict__ dn,
    const float* __restrict__ de, const float* __restrict__ Hb,
    const float* __restrict__ SpP, const float* __restrict__ TfP,
    const float* __restrict__ TpP, const float* __restrict__ cpP,
    float* __restrict__ Sp, float* __restrict__ Sm,
    float* __restrict__ Tp, float* __restrict__ Tm,
    float* __restrict__ cpF) {
  const int SZ = NN * HH;
  int idx = blockIdx.x * 256 + threadIdx.x;
  int i = idx >> 6, c = idx & 63;
  float hic = h[idx];
  float dni = dn[i], dei = de[i];
  float sp = SpP[idx] + SpP[SZ + idx];
  float tf = TfP[idx] + TfP[SZ + idx];
  float tp = TpP[idx] + TpP[SZ + idx];
  // remove diagonal contributions (A = adj - diag)
  sp -= (dni > 0.f) ? hic : 0.f;
  tf -= dei * hic;
  tp -= fmaxf(dei, 0.f) * hic;
  Sp[idx] = sp;
  Sm[idx] = Hb[c] - hic - sp;  // (A<0)@h = rowsum_off_diag - (A>0)@h
  Tp[idx] = tp;
  Tm[idx] = tf - tp;
  if (idx < NN) {
    float cnt = cpP[idx] + cpP[NN + idx];
    cnt -= (de[idx] > 0.f) ? 1.f : 0.f;
    cpF[idx] = cnt;
  }
}

// ---------------------------------------------------------------- [N,64] @ [64,64]
__global__ __launch_bounds__(256) void k_mm64(const float* __restrict__ X,
                                              const float* __restrict__ W,
                                              float* __restrict__ Y) {
  __shared__ float Ws[64][64];
  __shared__ float Xs[16][64];
  const int t = threadIdx.x;
  for (int l = t; l < 4096; l += 256) Ws[l >> 6][l & 63] = W[l];
  const int i0 = blockIdx.x * 16;
  for (int l = t; l < 1024; l += 256)
    Xs[l >> 6][l & 63] = X[(size_t)(i0 + (l >> 6)) * 64 + (l & 63)];
  __syncthreads();
  const int lane = t & 63, wid = t >> 6;
  float acc[4] = {0.f, 0.f, 0.f, 0.f};
  for (int k = 0; k < 64; ++k) {
    float wv = Ws[k][lane];
#pragma unroll
    for (int r = 0; r < 4; ++r) acc[r] += Xs[wid * 4 + r][k] * wv;
  }
#pragma unroll
  for (int r = 0; r < 4; ++r) Y[(size_t)(i0 + wid * 4 + r) * 64 + lane] = acc[r];
}

// ---------------------------------------------------------------- analytic GAT softmax
__global__ __launch_bounds__(256) void k_gat(
    const float* __restrict__ HP, const float* __restrict__ HM,
    const float* __restrict__ a, const float* __restrict__ Tp,
    const float* __restrict__ Tm, const float* __restrict__ cpF,
    float* __restrict__ U) {
  const int lane = threadIdx.x & 63;
  const int i = blockIdx.x * 4 + (threadIdx.x >> 6);
  const int idx = i * 64 + lane;
  float hp = HP[idx], hm = HM[idx];
  float a0 = a[lane], a1 = a[64 + lane];
  float ep = hp * a0 + hm * a1;
  float em = hm * a0 + hp * a1;
#pragma unroll
  for (int off = 32; off >= 1; off >>= 1) {
    ep += __shfl_xor(ep, off);
    em += __shfl_xor(em, off);
  }
  ep = ep > 0.f ? ep : LALPHA * ep;
  em = em > 0.f ? em : LALPHA * em;
  float cp = cpF[i];
  float cm = (float)(NN - 1) - cp;
  const float NEGI = -3.0e38f;
  float m = fmaxf(cp > 0.f ? ep : NEGI, cm > 0.f ? em : NEGI);
  float xp = (cp > 0.f) ? expf(ep - m) : 0.f;
  float xm = (cm > 0.f) ? expf(em - m) : 0.f;
  float denom = cp * xp + cm * xm;
  float inv = denom > 0.f ? 1.f / denom : 0.f;
  float wp = xp * inv, wm = xm * inv;
  U[idx] = wp * Tp[idx] + wm * Tm[idx];
}

// ---------------------------------------------------------------- GRU cell (r,z,n)
template <int XK>
__global__ __launch_bounds__(64) void k_gru(
    const float* __restrict__ x1, const float* __restrict__ x2,
    const float* __restrict__ wih, const float* __restrict__ whh,
    const float* __restrict__ bih, const float* __restrict__ bhh,
    const float* __restrict__ h, float* __restrict__ out) {
  const int c = threadIdx.x;
  const int i0 = blockIdx.x * 8;
  __shared__ float xs[8][XK];
  __shared__ float hs[8][64];
  for (int l = c; l < 8 * XK; l += 64) {
    int r = l / XK, k = l % XK;
    float v;
    if (XK == 128)
      v = (k < 64) ? x1[(size_t)(i0 + r) * 64 + k]
                   : x2[(size_t)(i0 + r) * 64 + (k - 64)];
    else
      v = x1[(size_t)(i0 + r) * 64 + k];
    xs[r][k] = v;
  }
  for (int l = c; l < 8 * 64; l += 64) {
    int r = l >> 6, k = l & 63;
    hs[r][k] = h[(size_t)(i0 + r) * 64 + k];
  }
  __syncthreads();
  float gr[8] = {}, gz[8] = {}, gn[8] = {};
  for (int k = 0; k < XK; ++k) {
    float wr = wih[(size_t)c * XK + k];
    float wz = wih[(size_t)(64 + c) * XK + k];
    float wn = wih[(size_t)(128 + c) * XK + k];
#pragma unroll
    for (int r = 0; r < 8; ++r) {
      float xv = xs[r][k];
      gr[r] += xv * wr; gz[r] += xv * wz; gn[r] += xv * wn;
    }
  }
  float hr[8] = {}, hz[8] = {}, hn[8] = {};
  for (int k = 0; k < 64; ++k) {
    float ur = whh[(size_t)c * 64 + k];
    float uz = whh[(size_t)(64 + c) * 64 + k];
    float un = whh[(size_t)(128 + c) * 64 + k];
#pragma unroll
    for (int r = 0; r < 8; ++r) {
      float hv = hs[r][k];
      hr[r] += hv * ur; hz[r] += hv * uz; hn[r] += hv * un;
    }
  }
  float br = bih[c], bz = bih[64 + c], bn = bih[128 + c];
  float dr = bhh[c], dz = bhh[64 + c], dnb = bhh[128 + c];
#pragma unroll
  for (int r = 0; r < 8; ++r) {
    float rg = 1.f / (1.f + expf(-(gr[r] + br + hr[r] + dr)));
    float zg = 1.f / (1.f + expf(-(gz[r] + bz + hz[r] + dz)));
    float ng = tanhf(gn[r] + bn + rg * (hn[r] + dnb));
    out[(size_t)(i0 + r) * 64 + c] = (1.f - zg) * ng + zg * hs[r][c];
  }
}

// ---------------------------------------------------------------- final combine
__global__ __launch_bounds__(256) void k_final(const float* __restrict__ dn,
                                               const float* __restrict__ de,
                                               const float* __restrict__ EO,
                                               const float* __restrict__ NO,
                                               float* __restrict__ out) {
  int idx = blockIdx.x * 256 + threadIdx.x;
  int i = idx >> 6;
  out[idx] = de[i] * EO[idx] + dn[i] * NO[idx];
}

extern "C" void kernel_launch(void* const* d_in, const int* in_sizes, int n_in,
                              void* d_out, int out_size, void* d_ws, size_t ws_size,
                              hipStream_t stream) {
  const float* h    = (const float*)d_in[0];
  const float* na   = (const float*)d_in[1];
  const float* ea   = (const float*)d_in[2];
  const float* Wg   = (const float*)d_in[3];
  const float* ag   = (const float*)d_in[4];
  const float* wihe = (const float*)d_in[5];
  const float* whhe = (const float*)d_in[6];
  const float* bihe = (const float*)d_in[7];
  const float* bhhe = (const float*)d_in[8];
  const float* wihn = (const float*)d_in[9];
  const float* whhn = (const float*)d_in[10];
  const float* bihn = (const float*)d_in[11];
  const float* bhhn = (const float*)d_in[12];
  float* out = (float*)d_out;
  float* ws  = (float*)d_ws;

  const size_t SZ = (size_t)NN * HH;
  float* SpP = ws;               // 2*SZ
  float* TfP = ws + 2 * SZ;      // 2*SZ
  float* TpP = ws + 4 * SZ;      // 2*SZ
  float* Sp  = ws + 6 * SZ;
  float* Sm  = ws + 7 * SZ;
  float* Tp  = ws + 8 * SZ;
  float* Tm  = ws + 9 * SZ;
  float* HP  = ws + 10 * SZ;
  float* HM  = ws + 11 * SZ;
  float* U   = ws + 12 * SZ;
  float* ES  = ws + 13 * SZ;
  float* EO  = ws + 14 * SZ;
  float* NO  = ws + 15 * SZ;
  float* cpP = ws + 16 * SZ;     // 2*NN
  float* cpF = cpP + 2 * NN;     // NN
  float* dn  = cpF + NN;         // NN
  float* de  = dn + NN;          // NN
  float* HbP = de + NN;          // 64*64
  float* Hb  = HbP + 4096;       // 64

  k_diag<<<32, 256, 0, stream>>>(na, ea, dn, de);
  k_hbarP<<<64, 256, 0, stream>>>(h, HbP);
  k_hbarF<<<1, 64, 0, stream>>>(HbP, Hb);
  k_stageA<<<dim3(NN / 16, 2), 256, 0, stream>>>(na, ea, h, SpP, TfP, TpP, cpP);
  k_combine<<<(int)(SZ / 256), 256, 0, stream>>>(h, dn, de, Hb, SpP, TfP, TpP, cpP,
                                                 Sp, Sm, Tp, Tm, cpF);
  k_mm64<<<NN / 16, 256, 0, stream>>>(Sp, Wg, HP);
  k_mm64<<<NN / 16, 256, 0, stream>>>(Sm, Wg, HM);
  k_gat<<<NN / 4, 256, 0, stream>>>(HP, HM, ag, Tp, Tm, cpF, U);
  k_mm64<<<NN / 16, 256, 0, stream>>>(U, Wg, ES);
  k_gru<128><<<NN / 8, 64, 0, stream>>>(Sp, Sm, wihe, whhe, bihe, bhhe, h, EO);
  k_gru<64><<<NN / 8, 64, 0, stream>>>(ES, nullptr, wihn, whhn, bihn, bhhn, h, NO);
  k_final<<<(int)(SZ / 256), 256, 0, stream>>>(dn, de, EO, NO, out);
}

// Round 2
// 272.814 us; speedup vs baseline: 6.3533x; 6.3533x over previous
//
#include <hip/hip_runtime.h>

#define NN 8192
#define HH 64
#define KSPLIT 4
constexpr float LALPHA = 0.2f;

typedef __attribute__((ext_vector_type(8))) short bf16x8;
typedef __attribute__((ext_vector_type(4))) float f32x4;

__device__ inline short f2bf(float f) {
  unsigned u = __builtin_bit_cast(unsigned, f);
  u += 0x7FFFu + ((u >> 16) & 1u);
  return (short)(u >> 16);
}

// ---------------------------------------------------------------- diag extract
__global__ __launch_bounds__(256) void k_diag(const float* __restrict__ na,
                                              const float* __restrict__ ea,
                                              float* __restrict__ dn,
                                              float* __restrict__ de) {
  int i = blockIdx.x * 256 + threadIdx.x;
  if (i < NN) {
    dn[i] = na[(size_t)i * NN + i];
    de[i] = ea[(size_t)i * NN + i];
  }
}

// ---------------------------------------------------------------- column sums of h
__global__ __launch_bounds__(256) void k_hbarP(const float* __restrict__ h,
                                               float* __restrict__ HbP) {
  int c = threadIdx.x & 63, rs = threadIdx.x >> 6;
  int r0 = blockIdx.x * 128;
  float s = 0.f;
  for (int r = rs; r < 128; r += 4) s += h[(size_t)(r0 + r) * HH + c];
  __shared__ float red[4][64];
  red[rs][c] = s;
  __syncthreads();
  if (rs == 0) HbP[blockIdx.x * 64 + c] = red[0][c] + red[1][c] + red[2][c] + red[3][c];
}

__global__ __launch_bounds__(64) void k_hbarF(const float* __restrict__ HbP,
                                              float* __restrict__ Hb) {
  int c = threadIdx.x;
  float s = 0.f;
  for (int b = 0; b < 64; ++b) s += HbP[b * 64 + c];
  Hb[c] = s;
}

// ---------------------------------------------------------------- h -> ht (transposed bf16 [64][NN])
__global__ __launch_bounds__(256) void k_ht(const float* __restrict__ h,
                                            unsigned short* __restrict__ ht) {
  __shared__ float tile[64][65];
  int j0 = blockIdx.x * 64;
  for (int l = threadIdx.x; l < 64 * 64; l += 256) {
    int r = l >> 6, c = l & 63;
    tile[r][c] = h[(size_t)(j0 + r) * HH + c];
  }
  __syncthreads();
  for (int l = threadIdx.x; l < 64 * 64; l += 256) {
    int c = l >> 6, r = l & 63;
    ht[(size_t)c * NN + j0 + r] = (unsigned short)f2bf(tile[r][c]);
  }
}

// ---------------------------------------------------------------- heavy masked matmuls via MFMA
// Sp_raw = (na>0)@h, Tf_raw = ea@h, Tp_raw = relu(ea)@h, cp_raw = #(ea>0) per row
// mfma_f32_16x16x32_bf16: A[l&15][8*(l>>4)+j], B[8*(l>>4)+j][l&15], D[(l>>4)*4+r][l&15]
__global__ __launch_bounds__(256) void k_stageA(
    const float* __restrict__ na, const float* __restrict__ ea,
    const unsigned short* __restrict__ ht,
    float* __restrict__ SpP, float* __restrict__ TfP,
    float* __restrict__ TpP, float* __restrict__ cpP) {
  const int lane  = threadIdx.x & 63;
  const int wid   = threadIdx.x >> 6;
  const int row16 = lane & 15;
  const int kgrp  = lane >> 4;
  const int i0    = blockIdx.x * 64 + wid * 16;
  const int ks    = blockIdx.y;
  const int kbeg  = ks * (NN / KSPLIT);

  f32x4 accS[4] = {}, accF[4] = {}, accP[4] = {};
  float cnt = 0.f;

  const float* naRow = na + (size_t)(i0 + row16) * NN;
  const float* eaRow = ea + (size_t)(i0 + row16) * NN;

  for (int k0 = kbeg; k0 < kbeg + NN / KSPLIT; k0 += 32) {
    const int kk = k0 + kgrp * 8;
    const float4 a0 = *reinterpret_cast<const float4*>(naRow + kk);
    const float4 a1 = *reinterpret_cast<const float4*>(naRow + kk + 4);
    const float4 e0 = *reinterpret_cast<const float4*>(eaRow + kk);
    const float4 e1 = *reinterpret_cast<const float4*>(eaRow + kk + 4);
    const float av[8] = {a0.x, a0.y, a0.z, a0.w, a1.x, a1.y, a1.z, a1.w};
    const float ev[8] = {e0.x, e0.y, e0.z, e0.w, e1.x, e1.y, e1.z, e1.w};
    bf16x8 fS, fF, fP;
#pragma unroll
    for (int q = 0; q < 8; ++q) {
      fS[q] = (av[q] > 0.f) ? (short)0x3F80 : (short)0;
      fF[q] = f2bf(ev[q]);
      fP[q] = f2bf(fmaxf(ev[q], 0.f));
      cnt += (ev[q] > 0.f) ? 1.f : 0.f;
    }
#pragma unroll
    for (int c = 0; c < 4; ++c) {
      const bf16x8 fB = *reinterpret_cast<const bf16x8*>(
          ht + (size_t)(c * 16 + row16) * NN + kk);
      accS[c] = __builtin_amdgcn_mfma_f32_16x16x32_bf16(fS, fB, accS[c], 0, 0, 0);
      accF[c] = __builtin_amdgcn_mfma_f32_16x16x32_bf16(fF, fB, accF[c], 0, 0, 0);
      accP[c] = __builtin_amdgcn_mfma_f32_16x16x32_bf16(fP, fB, accP[c], 0, 0, 0);
    }
  }
  cnt += __shfl_xor(cnt, 16);
  cnt += __shfl_xor(cnt, 32);
  if (lane < 16) cpP[ks * NN + i0 + lane] = cnt;

  const size_t base = (size_t)ks * ((size_t)NN * HH);
#pragma unroll
  for (int c = 0; c < 4; ++c) {
#pragma unroll
    for (int r = 0; r < 4; ++r) {
      const int row = i0 + kgrp * 4 + r;
      const int col = c * 16 + row16;
      const size_t idx = base + (size_t)row * HH + col;
      SpP[idx] = accS[c][r];
      TfP[idx] = accF[c][r];
      TpP[idx] = accP[c][r];
    }
  }
}

// ---------------------------------------------------------------- combine partials
__global__ __launch_bounds__(256) void k_combine(
    const float* __restrict__ h, const float* __restrict__ dn,
    const float* __restrict__ de, const float* __restrict__ Hb,
    float* __restrict__ SpP, float* __restrict__ TfP,
    float* __restrict__ TpP, const float* __restrict__ cpP,
    float* __restrict__ cpF) {
  const int SZ = NN * HH;
  int idx = blockIdx.x * 256 + threadIdx.x;
  int i = idx >> 6, c = idx & 63;
  float hic = h[idx];
  float dni = dn[i], dei = de[i];
  float sp = SpP[idx] + SpP[SZ + idx] + SpP[2 * SZ + idx] + SpP[3 * SZ + idx];
  float tf = TfP[idx] + TfP[SZ + idx] + TfP[2 * SZ + idx] + TfP[3 * SZ + idx];
  float tp = TpP[idx] + TpP[SZ + idx] + TpP[2 * SZ + idx] + TpP[3 * SZ + idx];
  // remove diagonal contributions (A = adj - diag)
  sp -= (dni > 0.f) ? hic : 0.f;
  tf -= dei * hic;
  tp -= fmaxf(dei, 0.f) * hic;
  // finals alias onto partial buffers (same-thread read-before-write only)
  SpP[idx] = sp;                       // Sp
  SpP[SZ + idx] = Hb[c] - hic - sp;    // Sm
  TpP[idx] = tp;                       // Tp
  TpP[SZ + idx] = tf - tp;             // Tm
  if (idx < NN) {
    float cntv = cpP[idx] + cpP[NN + idx] + cpP[2 * NN + idx] + cpP[3 * NN + idx];
    cntv -= (de[idx] > 0.f) ? 1.f : 0.f;
    cpF[idx] = cntv;
  }
}

// ---------------------------------------------------------------- [N,64] @ [64,64]
__global__ __launch_bounds__(256) void k_mm64(const float* __restrict__ X,
                                              const float* __restrict__ W,
                                              float* __restrict__ Y) {
  __shared__ float Ws[64][64];
  __shared__ float Xs[16][64];
  const int t = threadIdx.x;
  for (int l = t; l < 4096; l += 256) Ws[l >> 6][l & 63] = W[l];
  const int i0 = blockIdx.x * 16;
  for (int l = t; l < 1024; l += 256)
    Xs[l >> 6][l & 63] = X[(size_t)(i0 + (l >> 6)) * 64 + (l & 63)];
  __syncthreads();
  const int lane = t & 63, wid = t >> 6;
  float acc[4] = {0.f, 0.f, 0.f, 0.f};
  for (int k = 0; k < 64; ++k) {
    float wv = Ws[k][lane];
#pragma unroll
    for (int r = 0; r < 4; ++r) acc[r] += Xs[wid * 4 + r][k] * wv;
  }
#pragma unroll
  for (int r = 0; r < 4; ++r) Y[(size_t)(i0 + wid * 4 + r) * 64 + lane] = acc[r];
}

// ---------------------------------------------------------------- analytic GAT softmax
__global__ __launch_bounds__(256) void k_gat(
    const float* __restrict__ HP, const float* __restrict__ HM,
    const float* __restrict__ a, const float* __restrict__ Tp,
    const float* __restrict__ Tm, const float* __restrict__ cpF,
    float* __restrict__ U) {
  const int lane = threadIdx.x & 63;
  const int i = blockIdx.x * 4 + (threadIdx.x >> 6);
  const int idx = i * 64 + lane;
  float hp = HP[idx], hm = HM[idx];
  float a0 = a[lane], a1 = a[64 + lane];
  float ep = hp * a0 + hm * a1;
  float em = hm * a0 + hp * a1;
#pragma unroll
  for (int off = 32; off >= 1; off >>= 1) {
    ep += __shfl_xor(ep, off);
    em += __shfl_xor(em, off);
  }
  ep = ep > 0.f ? ep : LALPHA * ep;
  em = em > 0.f ? em : LALPHA * em;
  float cp = cpF[i];
  float cm = (float)(NN - 1) - cp;
  const float NEGI = -3.0e38f;
  float m = fmaxf(cp > 0.f ? ep : NEGI, cm > 0.f ? em : NEGI);
  float xp = (cp > 0.f) ? expf(ep - m) : 0.f;
  float xm = (cm > 0.f) ? expf(em - m) : 0.f;
  float denom = cp * xp + cm * xm;
  float inv = denom > 0.f ? 1.f / denom : 0.f;
  float wp = xp * inv, wm = xm * inv;
  U[idx] = wp * Tp[idx] + wm * Tm[idx];
}

// ---------------------------------------------------------------- GRU cell (r,z,n)
template <int XK>
__global__ __launch_bounds__(64) void k_gru(
    const float* __restrict__ x1, const float* __restrict__ x2,
    const float* __restrict__ wih, const float* __restrict__ whh,
    const float* __restrict__ bih, const float* __restrict__ bhh,
    const float* __restrict__ h, float* __restrict__ out) {
  const int c = threadIdx.x;
  const int i0 = blockIdx.x * 8;
  __shared__ float xs[8][XK];
  __shared__ float hs[8][64];
  for (int l = c; l < 8 * XK; l += 64) {
    int r = l / XK, k = l % XK;
    float v;
    if (XK == 128)
      v = (k < 64) ? x1[(size_t)(i0 + r) * 64 + k]
                   : x2[(size_t)(i0 + r) * 64 + (k - 64)];
    else
      v = x1[(size_t)(i0 + r) * 64 + k];
    xs[r][k] = v;
  }
  for (int l = c; l < 8 * 64; l += 64) {
    int r = l >> 6, k = l & 63;
    hs[r][k] = h[(size_t)(i0 + r) * 64 + k];
  }
  __syncthreads();
  float gr[8] = {}, gz[8] = {}, gn[8] = {};
  for (int k = 0; k < XK; ++k) {
    float wr = wih[(size_t)c * XK + k];
    float wz = wih[(size_t)(64 + c) * XK + k];
    float wn = wih[(size_t)(128 + c) * XK + k];
#pragma unroll
    for (int r = 0; r < 8; ++r) {
      float xv = xs[r][k];
      gr[r] += xv * wr; gz[r] += xv * wz; gn[r] += xv * wn;
    }
  }
  float hr[8] = {}, hz[8] = {}, hn[8] = {};
  for (int k = 0; k < 64; ++k) {
    float ur = whh[(size_t)c * 64 + k];
    float uz = whh[(size_t)(64 + c) * 64 + k];
    float un = whh[(size_t)(128 + c) * 64 + k];
#pragma unroll
    for (int r = 0; r < 8; ++r) {
      float hv = hs[r][k];
      hr[r] += hv * ur; hz[r] += hv * uz; hn[r] += hv * un;
    }
  }
  float br = bih[c], bz = bih[64 + c], bn = bih[128 + c];
  float dr = bhh[c], dz = bhh[64 + c], dnb = bhh[128 + c];
#pragma unroll
  for (int r = 0; r < 8; ++r) {
    float rg = 1.f / (1.f + expf(-(gr[r] + br + hr[r] + dr)));
    float zg = 1.f / (1.f + expf(-(gz[r] + bz + hz[r] + dz)));
    float ng = tanhf(gn[r] + bn + rg * (hn[r] + dnb));
    out[(size_t)(i0 + r) * 64 + c] = (1.f - zg) * ng + zg * hs[r][c];
  }
}

// ---------------------------------------------------------------- final combine
__global__ __launch_bounds__(256) void k_final(const float* __restrict__ dn,
                                               const float* __restrict__ de,
                                               const float* __restrict__ EO,
                                               const float* __restrict__ NO,
                                               float* __restrict__ out) {
  int idx = blockIdx.x * 256 + threadIdx.x;
  int i = idx >> 6;
  out[idx] = de[i] * EO[idx] + dn[i] * NO[idx];
}

extern "C" void kernel_launch(void* const* d_in, const int* in_sizes, int n_in,
                              void* d_out, int out_size, void* d_ws, size_t ws_size,
                              hipStream_t stream) {
  const float* h    = (const float*)d_in[0];
  const float* na   = (const float*)d_in[1];
  const float* ea   = (const float*)d_in[2];
  const float* Wg   = (const float*)d_in[3];
  const float* ag   = (const float*)d_in[4];
  const float* wihe = (const float*)d_in[5];
  const float* whhe = (const float*)d_in[6];
  const float* bihe = (const float*)d_in[7];
  const float* bhhe = (const float*)d_in[8];
  const float* wihn = (const float*)d_in[9];
  const float* whhn = (const float*)d_in[10];
  const float* bihn = (const float*)d_in[11];
  const float* bhhn = (const float*)d_in[12];
  float* out = (float*)d_out;
  float* ws  = (float*)d_ws;

  const size_t SZ = (size_t)NN * HH;
  float* SpP = ws;                // 4*SZ partials; finals: Sp=+0, Sm=+SZ
  float* TfP = ws + 4 * SZ;       // 4*SZ partials; finals: HP=+0, HM=+SZ, U=+2SZ, ES=+3SZ
  float* TpP = ws + 8 * SZ;       // 4*SZ partials; finals: Tp=+0, Tm=+SZ, EO=+2SZ, NO=+3SZ
  float* Sp = SpP;
  float* Sm = SpP + SZ;
  float* HP = TfP;
  float* HM = TfP + SZ;
  float* U  = TfP + 2 * SZ;
  float* ES = TfP + 3 * SZ;
  float* Tp = TpP;
  float* Tm = TpP + SZ;
  float* EO = TpP + 2 * SZ;
  float* NO = TpP + 3 * SZ;
  float* small = ws + 12 * SZ;
  float* cpP = small;             // 4*NN
  float* cpF = cpP + 4 * NN;      // NN
  float* dn  = cpF + NN;          // NN
  float* de  = dn + NN;           // NN
  float* HbP = de + NN;           // 4096
  float* Hb  = HbP + 4096;        // 64
  unsigned short* ht = (unsigned short*)(Hb + 64);  // 64*NN bf16

  k_diag<<<32, 256, 0, stream>>>(na, ea, dn, de);
  k_hbarP<<<64, 256, 0, stream>>>(h, HbP);
  k_hbarF<<<1, 64, 0, stream>>>(HbP, Hb);
  k_ht<<<NN / 64, 256, 0, stream>>>(h, ht);
  k_stageA<<<dim3(NN / 64, KSPLIT), 256, 0, stream>>>(na, ea, ht, SpP, TfP, TpP, cpP);
  k_combine<<<(int)(SZ / 256), 256, 0, stream>>>(h, dn, de, Hb, SpP, TfP, TpP, cpP, cpF);
  k_mm64<<<NN / 16, 256, 0, stream>>>(Sp, Wg, HP);
  k_mm64<<<NN / 16, 256, 0, stream>>>(Sm, Wg, HM);
  k_gat<<<NN / 4, 256, 0, stream>>>(HP, HM, ag, Tp, Tm, cpF, U);
  k_mm64<<<NN / 16, 256, 0, stream>>>(U, Wg, ES);
  k_gru<128><<<NN / 8, 64, 0, stream>>>(Sp, Sm, wihe, whhe, bihe, bhhe, h, EO);
  k_gru<64><<<NN / 8, 64, 0, stream>>>(ES, nullptr, wihn, whhn, bihn, bhhn, h, NO);
  k_final<<<(int)(SZ / 256), 256, 0, stream>>>(dn, de, EO, NO, out);
}